// Round 2
// baseline (14068.616 us; speedup 1.0000x reference)
//
#include <hip/hip_runtime.h>
#include <stdint.h>

#define H 512
#define B_SZ 1024
#define T_WARM 256
#define NSTEPS 64
#define TOTAL_T (T_WARM + NSTEPS)

#define RPB 32          // rows per team
#define HC 64           // cols per block
#define NTEAM 32        // B_SZ / RPB
#define NCG 8           // H / HC
#define NBLK 256        // NTEAM * NCG  (== CU count, 1 block/CU, co-resident)
#define NTHR 512        // 8 waves
#define HSTR 520        // padded LDS k-stride (ushorts); 1040B row stride = 16B aligned

typedef __attribute__((ext_vector_type(8))) short bf16x8;
typedef __attribute__((ext_vector_type(4))) float f32x4;

__device__ __forceinline__ ushort f2bf(float f) {
    uint32_t u = __builtin_bit_cast(uint32_t, f);
    u += 0x7FFFu + ((u >> 16) & 1u);
    return (ushort)(u >> 16);
}
__device__ __forceinline__ float bf2f(ushort h) {
    uint32_t u = ((uint32_t)h) << 16;
    return __builtin_bit_cast(float, u);
}

// prep: split W into bf16 hi/lo, bias = b_ih+b_hh, transpose x -> (T,B),
// zero h-buffer 0 and team counters. 1024 blocks x 512 thr = 524288 threads.
__global__ void prep_kernel(const float* __restrict__ x,
                            const float* __restrict__ W_hh,
                            const float* __restrict__ b_ih,
                            const float* __restrict__ b_hh,
                            ushort* __restrict__ Wh, ushort* __restrict__ Wl,
                            float* __restrict__ bias, float* __restrict__ xT,
                            uint32_t* __restrict__ Hb0, uint32_t* __restrict__ cnt) {
    int i = blockIdx.x * NTHR + threadIdx.x;     // [0, 524288)
    Hb0[i] = 0u;                                  // h(0) = 0, 1024*512 words
    if (i < 2048) cnt[i] = 0u;
    if (i < H * H) {
        float w = W_hh[i];
        ushort hi = f2bf(w);
        float rem = w - bf2f(hi);
        Wh[i] = hi;
        Wl[i] = f2bf(rem);
    }
    if (i < B_SZ * T_WARM) {
        int b = i & (B_SZ - 1), t = i >> 10;
        xT[t * B_SZ + b] = x[b * T_WARM + t];
    }
    if (i < H) bias[i] = b_ih[i] + b_hh[i];
}

__global__ __launch_bounds__(NTHR, 2)
void rnn_kernel(const float* __restrict__ xT,
                const float* __restrict__ W_ih,
                const float* __restrict__ b_fc_p,
                const float* __restrict__ W_fc,
                const ushort* __restrict__ Wh_g,
                const ushort* __restrict__ Wl_g,
                const float* __restrict__ bias_g,
                uint32_t* __restrict__ Hb0, uint32_t* __restrict__ Hb1,
                uint32_t* __restrict__ cnt,
                float* __restrict__ out) {
    __shared__ ushort Whs[HC * HSTR];      // 66560 B, resident all steps
    __shared__ ushort h_hi[RPB * HSTR];    // 33280 B
    __shared__ ushort h_lo[RPB * HSTR];    // 33280 B
    __shared__ float w_fc_s[H];
    __shared__ float w_in_s[HC];
    __shared__ float bias_s[HC];
    __shared__ float sx[RPB];
    __shared__ float sy[RPB];

    const int tid = threadIdx.x;
    const int bid = blockIdx.x;
    const int team = bid & (NTEAM - 1);    // bid&31: team blocks share XCD (bid%8 const)
    const int cg = bid >> 5;
    const int row0 = team * RPB;
    const int col0 = cg * HC;

    // ---- one-time staging: Wh slice (64 cols x 512 k) -> LDS, params ----
    #pragma unroll
    for (int it = 0; it < 8; ++it) {
        int chunk = it * NTHR + tid;               // 4096 chunks of 8 ushorts
        int c = chunk >> 6, k8 = (chunk & 63) << 3;
        uint4 v = *(const uint4*)(Wh_g + (col0 + c) * H + k8);
        *(uint4*)(&Whs[c * HSTR + k8]) = v;
    }
    w_fc_s[tid & (H - 1)] = W_fc[tid & (H - 1)];
    if (tid < HC) { w_in_s[tid] = W_ih[col0 + tid]; bias_s[tid] = bias_g[col0 + tid]; }
    const float bfc = b_fc_p[0];

    const int lane = tid & 63;
    const int wv = tid >> 6;
    const int n = lane & 15, q = lane >> 4;
    const int r2 = wv >> 2, c4 = wv & 3;           // wave tile: rows r2*16, cols c4*16
    const ushort* bl_g = Wl_g + (col0 + c4 * 16 + n) * H;  // Wl streamed (L2-resident slice)
    uint32_t* cbar = cnt + team * 64;              // 256B-padded per-team counter

    for (int t = 0; t < TOTAL_T; ++t) {
        // ---- wait for h(t) from the whole team ----
        if (t > 0) {
            const uint32_t target = (uint32_t)(NCG * t);
            while (__hip_atomic_load(cbar, __ATOMIC_ACQUIRE, __HIP_MEMORY_SCOPE_AGENT) < target)
                __builtin_amdgcn_s_sleep(2);
        }
        // ---- stage h(t) team slice (32 rows x 512, packed hi|lo) -> LDS ----
        const uint32_t* hb = (t & 1) ? Hb1 : Hb0;
        const uint64_t* src = (const uint64_t*)(hb + row0 * H);
        #pragma unroll
        for (int it = 0; it < 16; ++it) {
            int idx = it * NTHR + tid;             // 8192 u64 (2 elems each)
            uint64_t u = __hip_atomic_load(src + idx, __ATOMIC_RELAXED, __HIP_MEMORY_SCOPE_AGENT);
            int row = idx >> 8, k = (idx & 255) << 1;
            uint32_t w0 = (uint32_t)u, w1 = (uint32_t)(u >> 32);
            uint32_t hw = (w0 >> 16) | (w1 & 0xFFFF0000u);
            uint32_t lw = (w0 & 0xFFFFu) | (w1 << 16);
            *(uint32_t*)(&h_hi[row * HSTR + k]) = hw;
            *(uint32_t*)(&h_lo[row * HSTR + k]) = lw;
        }
        if (t < T_WARM && tid < RPB) sx[tid] = xT[t * B_SZ + row0 + tid];
        __syncthreads();

        // ---- rollout: y = h . w_fc + b_fc (redundant per cg; cg0 writes out) ----
        if (t >= T_WARM) {
            int r = tid >> 4, seg = tid & 15;
            const ushort* hh = &h_hi[r * HSTR];
            const ushort* hl = &h_lo[r * HSTR];
            float s = 0.f;
            #pragma unroll
            for (int kk = 0; kk < 32; ++kk) {
                int k = seg * 32 + kk;
                s += (bf2f(hh[k]) + bf2f(hl[k])) * w_fc_s[k];
            }
            #pragma unroll
            for (int off = 8; off; off >>= 1) s += __shfl_down(s, off, 16);
            if (seg == 0) {
                float y = s + bfc;
                sy[r] = y;
                if (cg == 0) out[(row0 + r) * NSTEPS + (t - T_WARM)] = y;
            }
            __syncthreads();
        }

        // ---- MFMA: D(16x16) += h(16x512) @ W^T slice, 3 hi/lo terms ----
        f32x4 acc0 = {0.f, 0.f, 0.f, 0.f}, acc1 = {0.f, 0.f, 0.f, 0.f};
        const ushort* ha = &h_hi[(r2 * 16 + n) * HSTR];
        const ushort* la = &h_lo[(r2 * 16 + n) * HSTR];
        const ushort* wb = &Whs[(c4 * 16 + n) * HSTR];
        #pragma unroll
        for (int kt = 0; kt < 16; kt += 2) {
            {
                const int kb = kt * 32 + q * 8;
                bf16x8 ah = *(const bf16x8*)(ha + kb);
                bf16x8 al = *(const bf16x8*)(la + kb);
                bf16x8 bh = *(const bf16x8*)(wb + kb);
                bf16x8 bl = *(const bf16x8*)(bl_g + kt * 32 + q * 8);
                acc0 = __builtin_amdgcn_mfma_f32_16x16x32_bf16(ah, bh, acc0, 0, 0, 0);
                acc0 = __builtin_amdgcn_mfma_f32_16x16x32_bf16(al, bh, acc0, 0, 0, 0);
                acc0 = __builtin_amdgcn_mfma_f32_16x16x32_bf16(ah, bl, acc0, 0, 0, 0);
            }
            {
                const int kb = (kt + 1) * 32 + q * 8;
                bf16x8 ah = *(const bf16x8*)(ha + kb);
                bf16x8 al = *(const bf16x8*)(la + kb);
                bf16x8 bh = *(const bf16x8*)(wb + kb);
                bf16x8 bl = *(const bf16x8*)(bl_g + (kt + 1) * 32 + q * 8);
                acc1 = __builtin_amdgcn_mfma_f32_16x16x32_bf16(ah, bh, acc1, 0, 0, 0);
                acc1 = __builtin_amdgcn_mfma_f32_16x16x32_bf16(al, bh, acc1, 0, 0, 0);
                acc1 = __builtin_amdgcn_mfma_f32_16x16x32_bf16(ah, bl, acc1, 0, 0, 0);
            }
        }

        // ---- epilogue: v = acc + s*w_in + bias, relu, pack hi|lo, publish ----
        const int jl = c4 * 16 + n;
        const float wi = w_in_s[jl], bj = bias_s[jl];
        uint32_t* dst = ((t & 1) ? Hb0 : Hb1) + col0 + jl;
        #pragma unroll
        for (int i = 0; i < 4; ++i) {
            int m = r2 * 16 + q * 4 + i;           // C/D: row = quad*4+reg, col = lane&15
            float sv = (t < T_WARM) ? sx[m] : sy[m];
            float v = acc0[i] + acc1[i] + sv * wi + bj;
            v = fmaxf(v, 0.f);
            ushort hi = f2bf(v);
            float rem = v - bf2f(hi);
            uint32_t u = ((uint32_t)hi << 16) | (uint32_t)f2bf(rem);
            __hip_atomic_store(dst + (row0 + m) * H, u, __ATOMIC_RELAXED, __HIP_MEMORY_SCOPE_AGENT);
        }
        __syncthreads();   // drains each wave's vmem (vmcnt0) before barrier
        if (tid == 0)
            __hip_atomic_fetch_add(cbar, 1u, __ATOMIC_RELEASE, __HIP_MEMORY_SCOPE_AGENT);
    }
}

extern "C" void kernel_launch(void* const* d_in, const int* in_sizes, int n_in,
                              void* d_out, int out_size, void* d_ws, size_t ws_size,
                              hipStream_t stream) {
    const float* x    = (const float*)d_in[0];
    const float* W_ih = (const float*)d_in[1];
    const float* W_hh = (const float*)d_in[2];
    const float* b_ih = (const float*)d_in[3];
    const float* b_hh = (const float*)d_in[4];
    const float* W_fc = (const float*)d_in[5];
    const float* b_fc = (const float*)d_in[6];
    float* out = (float*)d_out;

    // ws carve (bytes): Wh 512K | Wl 512K | bias 2K+pad | xT 1M | Hb0 2M | Hb1 2M | cnt 8K
    uint8_t* w = (uint8_t*)d_ws;
    ushort*   Wh   = (ushort*)(w);
    ushort*   Wl   = (ushort*)(w + 524288);
    float*    bias = (float*)(w + 1048576);
    float*    xT   = (float*)(w + 1052672);
    uint32_t* Hb0  = (uint32_t*)(w + 2101248);
    uint32_t* Hb1  = (uint32_t*)(w + 4198400);
    uint32_t* cnt  = (uint32_t*)(w + 6295552);

    prep_kernel<<<1024, NTHR, 0, stream>>>(x, W_hh, b_ih, b_hh, Wh, Wl, bias, xT, Hb0, cnt);
    rnn_kernel<<<NBLK, NTHR, 0, stream>>>(xT, W_ih, b_fc, W_fc, Wh, Wl, bias, Hb0, Hb1, cnt, out);
}

// Round 3
// 2218.382 us; speedup vs baseline: 6.3418x; 6.3418x over previous
//
#include <hip/hip_runtime.h>
#include <stdint.h>

#define H 512
#define B_SZ 1024
#define T_WARM 256
#define NSTEPS 64
#define TOTAL_T (T_WARM + NSTEPS)

#define RPB 32          // rows per team
#define HC 64           // cols per block
#define NTEAM 32        // B_SZ / RPB
#define NCG 8           // H / HC
#define NBLK 256        // NTEAM * NCG  (== CU count, 1 block/CU, co-resident)
#define NTHR 512        // 8 waves
#define HSTR 520        // padded LDS k-stride (ushorts); 1040B row stride = 16B aligned

typedef __attribute__((ext_vector_type(8))) short bf16x8;
typedef __attribute__((ext_vector_type(4))) float f32x4;

__device__ __forceinline__ ushort f2bf(float f) {
    uint32_t u = __builtin_bit_cast(uint32_t, f);
    u += 0x7FFFu + ((u >> 16) & 1u);
    return (ushort)(u >> 16);
}
__device__ __forceinline__ float bf2f(ushort h) {
    uint32_t u = ((uint32_t)h) << 16;
    return __builtin_bit_cast(float, u);
}

// prep: split W into bf16 hi/lo, bias = b_ih+b_hh, transpose x -> (T,B),
// zero h-buffer 0 and team counters. 1024 blocks x 512 thr = 524288 threads.
__global__ void prep_kernel(const float* __restrict__ x,
                            const float* __restrict__ W_hh,
                            const float* __restrict__ b_ih,
                            const float* __restrict__ b_hh,
                            ushort* __restrict__ Wh, ushort* __restrict__ Wl,
                            float* __restrict__ bias, float* __restrict__ xT,
                            uint32_t* __restrict__ Hb0, uint32_t* __restrict__ cnt) {
    int i = blockIdx.x * NTHR + threadIdx.x;     // [0, 524288)
    Hb0[i] = 0u;                                  // h(0) = 0, 1024*512 words
    if (i < 2048) cnt[i] = 0u;
    if (i < H * H) {
        float w = W_hh[i];
        ushort hi = f2bf(w);
        float rem = w - bf2f(hi);
        Wh[i] = hi;
        Wl[i] = f2bf(rem);
    }
    if (i < B_SZ * T_WARM) {
        int b = i & (B_SZ - 1), t = i >> 10;
        xT[t * B_SZ + b] = x[b * T_WARM + t];
    }
    if (i < H) bias[i] = b_ih[i] + b_hh[i];
}

__global__ __launch_bounds__(NTHR, 2)
void rnn_kernel(const float* __restrict__ xT,
                const float* __restrict__ W_ih,
                const float* __restrict__ b_fc_p,
                const float* __restrict__ W_fc,
                const ushort* __restrict__ Wh_g,
                const ushort* __restrict__ Wl_g,
                const float* __restrict__ bias_g,
                uint32_t* __restrict__ Hb0, uint32_t* __restrict__ Hb1,
                uint32_t* __restrict__ cnt,
                float* __restrict__ out) {
    __shared__ ushort Whs[HC * HSTR];      // 66560 B, resident all steps
    __shared__ ushort h_hi[RPB * HSTR];    // 33280 B
    __shared__ ushort h_lo[RPB * HSTR];    // 33280 B
    __shared__ float w_fc_s[H];
    __shared__ float w_in_s[HC];
    __shared__ float bias_s[HC];
    __shared__ float sx[RPB];
    __shared__ float sy[RPB];

    const int tid = threadIdx.x;
    const int bid = blockIdx.x;
    const int team = bid & (NTEAM - 1);    // bid&31: team blocks share XCD (bid%8 const) - perf only
    const int cg = bid >> 5;
    const int row0 = team * RPB;
    const int col0 = cg * HC;

    // ---- one-time staging: Wh slice (64 cols x 512 k) -> LDS, params ----
    #pragma unroll
    for (int it = 0; it < 8; ++it) {
        int chunk = it * NTHR + tid;               // 4096 chunks of 8 ushorts
        int c = chunk >> 6, k8 = (chunk & 63) << 3;
        uint4 v = *(const uint4*)(Wh_g + (col0 + c) * H + k8);
        *(uint4*)(&Whs[c * HSTR + k8]) = v;
    }
    w_fc_s[tid & (H - 1)] = W_fc[tid & (H - 1)];
    if (tid < HC) { w_in_s[tid] = W_ih[col0 + tid]; bias_s[tid] = bias_g[col0 + tid]; }
    const float bfc = b_fc_p[0];

    const int lane = tid & 63;
    const int wv = tid >> 6;
    const int n = lane & 15, q = lane >> 4;
    const int r2 = wv >> 2, c4 = wv & 3;           // wave tile: rows r2*16, cols c4*16
    const ushort* bl_g = Wl_g + (col0 + c4 * 16 + n) * H;  // Wl streamed (L2-resident slice)
    uint32_t* cbar = cnt + team * 64;              // 256B-padded per-team counter

    for (int t = 0; t < TOTAL_T; ++t) {
        // ---- wait for h(t) from the whole team: ONE thread polls, RELAXED (no cache inv) ----
        if (t > 0) {
            if (tid == 0) {
                const uint32_t target = (uint32_t)(NCG * t);
                while (__hip_atomic_load(cbar, __ATOMIC_RELAXED, __HIP_MEMORY_SCOPE_AGENT) < target)
                    __builtin_amdgcn_s_sleep(1);
            }
            __syncthreads();
        }
        // ---- stage h(t) team slice (32 rows x 512, packed hi|lo) -> LDS ----
        const uint32_t* hb = (t & 1) ? Hb1 : Hb0;
        const uint64_t* src = (const uint64_t*)(hb + row0 * H);
        #pragma unroll
        for (int it = 0; it < 16; ++it) {
            int idx = it * NTHR + tid;             // 8192 u64 (2 elems each)
            uint64_t u = __hip_atomic_load(src + idx, __ATOMIC_RELAXED, __HIP_MEMORY_SCOPE_AGENT);
            int row = idx >> 8, k = (idx & 255) << 1;
            uint32_t w0 = (uint32_t)u, w1 = (uint32_t)(u >> 32);
            uint32_t hw = (w0 >> 16) | (w1 & 0xFFFF0000u);
            uint32_t lw = (w0 & 0xFFFFu) | (w1 << 16);
            *(uint32_t*)(&h_hi[row * HSTR + k]) = hw;
            *(uint32_t*)(&h_lo[row * HSTR + k]) = lw;
        }
        if (t < T_WARM && tid < RPB) sx[tid] = xT[t * B_SZ + row0 + tid];
        __syncthreads();

        // ---- rollout: y = h . w_fc + b_fc (redundant per cg; cg0 writes out) ----
        if (t >= T_WARM) {
            int r = tid >> 4, seg = tid & 15;
            const ushort* hh = &h_hi[r * HSTR];
            const ushort* hl = &h_lo[r * HSTR];
            float s = 0.f;
            #pragma unroll
            for (int kk = 0; kk < 32; ++kk) {
                int k = seg + kk * 16;             // consecutive lanes -> consecutive banks
                s += (bf2f(hh[k]) + bf2f(hl[k])) * w_fc_s[k];
            }
            #pragma unroll
            for (int off = 8; off; off >>= 1) s += __shfl_down(s, off, 16);
            if (seg == 0) {
                float y = s + bfc;
                sy[r] = y;
                if (cg == 0) out[(row0 + r) * NSTEPS + (t - T_WARM)] = y;
            }
            __syncthreads();
        }

        // ---- MFMA: D(16x16) += h(16x512) @ W^T slice, 3 hi/lo terms ----
        f32x4 acc0 = {0.f, 0.f, 0.f, 0.f}, acc1 = {0.f, 0.f, 0.f, 0.f};
        const ushort* ha = &h_hi[(r2 * 16 + n) * HSTR];
        const ushort* la = &h_lo[(r2 * 16 + n) * HSTR];
        const ushort* wb = &Whs[(c4 * 16 + n) * HSTR];
        #pragma unroll
        for (int kt = 0; kt < 16; kt += 2) {
            {
                const int kb = kt * 32 + q * 8;
                bf16x8 ah = *(const bf16x8*)(ha + kb);
                bf16x8 al = *(const bf16x8*)(la + kb);
                bf16x8 bh = *(const bf16x8*)(wb + kb);
                bf16x8 bl = *(const bf16x8*)(bl_g + kt * 32 + q * 8);
                acc0 = __builtin_amdgcn_mfma_f32_16x16x32_bf16(ah, bh, acc0, 0, 0, 0);
                acc0 = __builtin_amdgcn_mfma_f32_16x16x32_bf16(al, bh, acc0, 0, 0, 0);
                acc0 = __builtin_amdgcn_mfma_f32_16x16x32_bf16(ah, bl, acc0, 0, 0, 0);
            }
            {
                const int kb = (kt + 1) * 32 + q * 8;
                bf16x8 ah = *(const bf16x8*)(ha + kb);
                bf16x8 al = *(const bf16x8*)(la + kb);
                bf16x8 bh = *(const bf16x8*)(wb + kb);
                bf16x8 bl = *(const bf16x8*)(bl_g + (kt + 1) * 32 + q * 8);
                acc1 = __builtin_amdgcn_mfma_f32_16x16x32_bf16(ah, bh, acc1, 0, 0, 0);
                acc1 = __builtin_amdgcn_mfma_f32_16x16x32_bf16(al, bh, acc1, 0, 0, 0);
                acc1 = __builtin_amdgcn_mfma_f32_16x16x32_bf16(ah, bl, acc1, 0, 0, 0);
            }
        }

        // ---- epilogue: v = acc + s*w_in + bias, relu, pack hi|lo, publish ----
        const int jl = c4 * 16 + n;
        const float wi = w_in_s[jl], bj = bias_s[jl];
        uint32_t* dst = ((t & 1) ? Hb0 : Hb1) + col0 + jl;
        #pragma unroll
        for (int i = 0; i < 4; ++i) {
            int m = r2 * 16 + q * 4 + i;           // C/D: row = quad*4+reg, col = lane&15
            float sv = (t < T_WARM) ? sx[m] : sy[m];
            float v = acc0[i] + acc1[i] + sv * wi + bj;
            v = fmaxf(v, 0.f);
            ushort hi = f2bf(v);
            float rem = v - bf2f(hi);
            uint32_t u = ((uint32_t)hi << 16) | (uint32_t)f2bf(rem);
            __hip_atomic_store(dst + (row0 + m) * H, u, __ATOMIC_RELAXED, __HIP_MEMORY_SCOPE_AGENT);
        }
        __syncthreads();   // drains each wave's vmem (vmcnt0) before flag increment
        if (tid == 0)
            __hip_atomic_fetch_add(cbar, 1u, __ATOMIC_RELAXED, __HIP_MEMORY_SCOPE_AGENT);
    }
}

extern "C" void kernel_launch(void* const* d_in, const int* in_sizes, int n_in,
                              void* d_out, int out_size, void* d_ws, size_t ws_size,
                              hipStream_t stream) {
    const float* x    = (const float*)d_in[0];
    const float* W_ih = (const float*)d_in[1];
    const float* W_hh = (const float*)d_in[2];
    const float* b_ih = (const float*)d_in[3];
    const float* b_hh = (const float*)d_in[4];
    const float* W_fc = (const float*)d_in[5];
    const float* b_fc = (const float*)d_in[6];
    float* out = (float*)d_out;

    // ws carve (bytes): Wh 512K | Wl 512K | bias 2K+pad | xT 1M | Hb0 2M | Hb1 2M | cnt 8K
    uint8_t* w = (uint8_t*)d_ws;
    ushort*   Wh   = (ushort*)(w);
    ushort*   Wl   = (ushort*)(w + 524288);
    float*    bias = (float*)(w + 1048576);
    float*    xT   = (float*)(w + 1052672);
    uint32_t* Hb0  = (uint32_t*)(w + 2101248);
    uint32_t* Hb1  = (uint32_t*)(w + 4198400);
    uint32_t* cnt  = (uint32_t*)(w + 6295552);

    prep_kernel<<<1024, NTHR, 0, stream>>>(x, W_hh, b_ih, b_hh, Wh, Wl, bias, xT, Hb0, cnt);
    rnn_kernel<<<NBLK, NTHR, 0, stream>>>(xT, W_ih, b_fc, W_fc, Wh, Wl, bias, Hb0, Hb1, cnt, out);
}

// Round 4
// 2059.921 us; speedup vs baseline: 6.8297x; 1.0769x over previous
//
#include <hip/hip_runtime.h>
#include <stdint.h>

#define H 512
#define B_SZ 1024
#define T_WARM 256
#define NSTEPS 64
#define TOTAL_T (T_WARM + NSTEPS)

#define RPB 32          // rows per team
#define HC 64           // cols per block
#define NTEAM 32        // B_SZ / RPB
#define NCG 8           // H / HC
#define NBLK 256        // NTEAM * NCG == CU count, 1 block/CU
#define NTHR 512        // 8 waves
#define HSTR 520        // padded LDS k-stride (ushorts)

typedef __attribute__((ext_vector_type(8))) short bf16x8;
typedef __attribute__((ext_vector_type(4))) float f32x4;

__device__ __forceinline__ ushort f2bf(float f) {
    uint32_t u = __builtin_bit_cast(uint32_t, f);
    u += 0x7FFFu + ((u >> 16) & 1u);
    return (ushort)(u >> 16);
}
__device__ __forceinline__ float bf2f(ushort h) {
    uint32_t u = ((uint32_t)h) << 16;
    return __builtin_bit_cast(float, u);
}

__global__ void prep_kernel(const float* __restrict__ x,
                            const float* __restrict__ W_hh,
                            const float* __restrict__ b_ih,
                            const float* __restrict__ b_hh,
                            ushort* __restrict__ Wh, ushort* __restrict__ Wl,
                            float* __restrict__ bias, float* __restrict__ xT,
                            uint32_t* __restrict__ Hb0, uint32_t* __restrict__ flags) {
    int i = blockIdx.x * NTHR + threadIdx.x;     // [0, 524288)
    Hb0[i] = 0u;                                  // h(0) = 0
    if (i < 4096) flags[i] = 0u;                  // 16 KB flag region
    if (i < H * H) {
        float w = W_hh[i];
        ushort hi = f2bf(w);
        float rem = w - bf2f(hi);
        Wh[i] = hi;
        Wl[i] = f2bf(rem);
    }
    if (i < B_SZ * T_WARM) {
        int b = i & (B_SZ - 1), t = i >> 10;
        xT[t * B_SZ + b] = x[b * T_WARM + t];
    }
    if (i < H) bias[i] = b_ih[i] + b_hh[i];
}

__global__ __launch_bounds__(NTHR, 1)
void rnn_kernel(const float* __restrict__ xT,
                const float* __restrict__ W_ih,
                const float* __restrict__ b_fc_p,
                const float* __restrict__ W_fc,
                const ushort* __restrict__ Wh_g,
                const ushort* __restrict__ Wl_g,
                const float* __restrict__ bias_g,
                uint32_t* __restrict__ Hb0, uint32_t* __restrict__ Hb1,
                uint32_t* __restrict__ flags,
                float* __restrict__ out) {
    __shared__ ushort h_hi[RPB * HSTR];    // 33280 B
    __shared__ ushort h_lo[RPB * HSTR];    // 33280 B
    __shared__ float w_fc_s[H];
    __shared__ float w_in_s[HC];
    __shared__ float bias_s[HC];
    __shared__ float sx[RPB];
    __shared__ float sy[RPB];

    const int tid = threadIdx.x;
    const int bid = blockIdx.x;
    const int team = bid & (NTEAM - 1);    // team blocks share XCD residue (perf only)
    const int cg = bid >> 5;
    const int row0 = team * RPB;
    const int col0 = cg * HC;

    w_fc_s[tid & (H - 1)] = W_fc[tid & (H - 1)];
    if (tid < HC) { w_in_s[tid] = W_ih[col0 + tid]; bias_s[tid] = bias_g[col0 + tid]; }
    const float bfc = b_fc_p[0];

    const int lane = tid & 63;
    const int wv = tid >> 6;
    const int n = lane & 15, q = lane >> 4;
    const int r2 = wv >> 2, c4 = wv & 3;   // wave tile: rows r2*16, cols c4*16

    // ---- weights register-resident for all 320 steps: 128 VGPRs ----
    bf16x8 Bh[16], Bl[16];
    {
        const ushort* wh = Wh_g + (col0 + c4 * 16 + n) * H + q * 8;
        const ushort* wl = Wl_g + (col0 + c4 * 16 + n) * H + q * 8;
        #pragma unroll
        for (int kt = 0; kt < 16; ++kt) {
            Bh[kt] = *(const bf16x8*)(wh + kt * 32);
            Bl[kt] = *(const bf16x8*)(wl + kt * 32);
        }
    }

    uint32_t* myflag = flags + (team * NCG + cg) * 16;   // producer flag (64B stride)
    const uint32_t* pollflag = flags + (team * NCG + wv) * 16;  // wave wv polls producer wv

    for (int t = 0; t < TOTAL_T; ++t) {
        // x prefetch (independent of h) before any waiting
        if (t < T_WARM && tid < RPB) sx[tid] = xT[t * B_SZ + row0 + tid];

        // ---- per-wave: wait for producer wv's slice, then stage it (8 KB) ----
        if (t > 0) {
            while (__hip_atomic_load(pollflag, __ATOMIC_RELAXED, __HIP_MEMORY_SCOPE_AGENT)
                   < (uint32_t)t)
                __builtin_amdgcn_s_sleep(1);
        }
        {
            const uint32_t* hb = (t & 1) ? Hb1 : Hb0;
            const uint64_t* src = (const uint64_t*)hb;
            // slice wv = k-cols [wv*64, wv*64+64) for rows row0..row0+31
            #pragma unroll
            for (int it = 0; it < 16; ++it) {
                int flat = it * 64 + lane;             // [0,1024): r = flat>>5, cpair = flat&31
                int r = flat >> 5, cpair = flat & 31;
                uint64_t u = __hip_atomic_load(src + ((row0 + r) * 256 + wv * 32 + cpair),
                                               __ATOMIC_RELAXED, __HIP_MEMORY_SCOPE_AGENT);
                uint32_t w0 = (uint32_t)u, w1 = (uint32_t)(u >> 32);
                uint32_t hw = (w0 >> 16) | (w1 & 0xFFFF0000u);
                uint32_t lw = (w0 & 0xFFFFu) | (w1 << 16);
                int k = wv * 64 + cpair * 2;
                *(uint32_t*)(&h_hi[r * HSTR + k]) = hw;
                *(uint32_t*)(&h_lo[r * HSTR + k]) = lw;
            }
        }
        __syncthreads();

        // ---- rollout: y = h . w_fc + b_fc (redundant per cg; cg0 writes out) ----
        if (t >= T_WARM) {
            int r = tid >> 4, seg = tid & 15;
            const ushort* hh = &h_hi[r * HSTR];
            const ushort* hl = &h_lo[r * HSTR];
            float s = 0.f;
            #pragma unroll
            for (int kk = 0; kk < 32; ++kk) {
                int k = seg + kk * 16;
                s += (bf2f(hh[k]) + bf2f(hl[k])) * w_fc_s[k];
            }
            #pragma unroll
            for (int off = 8; off; off >>= 1) s += __shfl_down(s, off, 16);
            if (seg == 0) {
                float y = s + bfc;
                sy[r] = y;
                if (cg == 0) out[(row0 + r) * NSTEPS + (t - T_WARM)] = y;
            }
            __syncthreads();
        }

        // ---- MFMA: 16 k-tiles x (2 ds_read_b128 + 3 MFMA), B in registers ----
        f32x4 acc0 = {0.f, 0.f, 0.f, 0.f}, acc1 = {0.f, 0.f, 0.f, 0.f};
        const ushort* ha = &h_hi[(r2 * 16 + n) * HSTR] + q * 8;
        const ushort* la = &h_lo[(r2 * 16 + n) * HSTR] + q * 8;
        #pragma unroll
        for (int kt = 0; kt < 16; kt += 2) {
            {
                bf16x8 ah = *(const bf16x8*)(ha + kt * 32);
                bf16x8 al = *(const bf16x8*)(la + kt * 32);
                acc0 = __builtin_amdgcn_mfma_f32_16x16x32_bf16(ah, Bh[kt], acc0, 0, 0, 0);
                acc0 = __builtin_amdgcn_mfma_f32_16x16x32_bf16(al, Bh[kt], acc0, 0, 0, 0);
                acc0 = __builtin_amdgcn_mfma_f32_16x16x32_bf16(ah, Bl[kt], acc0, 0, 0, 0);
            }
            {
                bf16x8 ah = *(const bf16x8*)(ha + (kt + 1) * 32);
                bf16x8 al = *(const bf16x8*)(la + (kt + 1) * 32);
                acc1 = __builtin_amdgcn_mfma_f32_16x16x32_bf16(ah, Bh[kt + 1], acc1, 0, 0, 0);
                acc1 = __builtin_amdgcn_mfma_f32_16x16x32_bf16(al, Bh[kt + 1], acc1, 0, 0, 0);
                acc1 = __builtin_amdgcn_mfma_f32_16x16x32_bf16(ah, Bl[kt + 1], acc1, 0, 0, 0);
            }
        }

        // ---- epilogue: v = acc + s*w_in + bias, relu, pack hi|lo, publish ----
        const int jl = c4 * 16 + n;
        const float wi = w_in_s[jl], bj = bias_s[jl];
        uint32_t* dst = ((t & 1) ? Hb0 : Hb1) + col0 + jl;
        #pragma unroll
        for (int i = 0; i < 4; ++i) {
            int m = r2 * 16 + q * 4 + i;           // C/D: row = quad*4+reg, col = lane&15
            float sv = (t < T_WARM) ? sx[m] : sy[m];
            float v = acc0[i] + acc1[i] + sv * wi + bj;
            v = fmaxf(v, 0.f);
            ushort hi = f2bf(v);
            float rem = v - bf2f(hi);
            uint32_t u = ((uint32_t)hi << 16) | (uint32_t)f2bf(rem);
            __hip_atomic_store(dst + (row0 + m) * H, u, __ATOMIC_RELAXED, __HIP_MEMORY_SCOPE_AGENT);
        }
        __syncthreads();   // vmcnt(0) drain of all waves' stores before flag publish
        if (tid == 0)
            __hip_atomic_store(myflag, (uint32_t)(t + 1), __ATOMIC_RELAXED, __HIP_MEMORY_SCOPE_AGENT);
    }
}

extern "C" void kernel_launch(void* const* d_in, const int* in_sizes, int n_in,
                              void* d_out, int out_size, void* d_ws, size_t ws_size,
                              hipStream_t stream) {
    const float* x    = (const float*)d_in[0];
    const float* W_ih = (const float*)d_in[1];
    const float* W_hh = (const float*)d_in[2];
    const float* b_ih = (const float*)d_in[3];
    const float* b_hh = (const float*)d_in[4];
    const float* W_fc = (const float*)d_in[5];
    const float* b_fc = (const float*)d_in[6];
    float* out = (float*)d_out;

    // ws carve (bytes): Wh 512K | Wl 512K | bias 4K | xT 1M | Hb0 2M | Hb1 2M | flags 16K
    uint8_t* w = (uint8_t*)d_ws;
    ushort*   Wh    = (ushort*)(w);
    ushort*   Wl    = (ushort*)(w + 524288);
    float*    bias  = (float*)(w + 1048576);
    float*    xT    = (float*)(w + 1052672);
    uint32_t* Hb0   = (uint32_t*)(w + 2101248);
    uint32_t* Hb1   = (uint32_t*)(w + 4198400);
    uint32_t* flags = (uint32_t*)(w + 6295552);

    prep_kernel<<<1024, NTHR, 0, stream>>>(x, W_hh, b_ih, b_hh, Wh, Wl, bias, xT, Hb0, flags);
    rnn_kernel<<<NBLK, NTHR, 0, stream>>>(xT, W_ih, b_fc, W_fc, Wh, Wl, bias, Hb0, Hb1, flags, out);
}